// Round 4
// baseline (283.692 us; speedup 1.0000x reference)
//
#include <hip/hip_runtime.h>
#include <hip/hip_bf16.h>
#include <stdint.h>

#define BATCH 64
#define CIN   64
#define LEN   4096
#define COUT  128
#define KW    7
#define LPOOL 2048
#define NT    4     // l sub-tiles of 64 per block
#define RROWS 72    // sign rows: p = l0-4+r, r in [0,72)
#define RAWP  80    // raw floats per ci row: p = l0-8+col, col in [0,80)

typedef __bf16 v8bf __attribute__((ext_vector_type(8)));
typedef unsigned short v8us __attribute__((ext_vector_type(8)));
typedef float  v4f  __attribute__((ext_vector_type(4)));

typedef const __attribute__((address_space(1))) void* gp1_t;
typedef __attribute__((address_space(3))) void* lp3_t;

// Convert conv_w [COUT][CIN][KW] fp32 -> Wt [KW][COUT][CIN] bf16 (RNE).
__global__ __launch_bounds__(256)
void wconv_kernel(const float* __restrict__ W, ushort* __restrict__ Wt) {
    int i = blockIdx.x * 256 + threadIdx.x;
    if (i >= COUT * CIN * KW) return;
    int co  = i / (CIN * KW);
    int rem = i - co * (CIN * KW);
    int ci  = rem / KW;
    int k   = rem - ci * KW;
    uint u = __float_as_uint(W[i]);
    uint r = (u + 0x7FFFu + ((u >> 16) & 1u)) >> 16;   // RNE to bf16
    Wt[(k * COUT + co) * CIN + ci] = (ushort)r;
}

// Fused: BN -> sign -> conv (bf16 MFMA) -> alpha -> PReLU -> maxpool2.
// Block: 256 threads, NT=4 l-sub-tiles. Staging via global_load_lds DMA
// (no VGPR staging => no spills). Per tile: binarize(t) | barrier |
// DMA(t+1) issue | MFMA(t)+stores | barrier (drains DMA under MFMA shadow).
__global__ __launch_bounds__(256, 4)
void conv_kernel(const float* __restrict__ I,
                 const float* __restrict__ bn_g, const float* __restrict__ bn_b,
                 const float* __restrict__ bn_m, const float* __restrict__ bn_v,
                 const ushort* __restrict__ Wt,
                 const float* __restrict__ alpha, const float* __restrict__ prelu,
                 float* __restrict__ out) {
    __shared__ __attribute__((aligned(16))) float  raw[CIN * RAWP];   // 20480 B
    __shared__ __attribute__((aligned(16))) ushort stg[RROWS * 72];   // 10368 B, pitch 144B
    __shared__ float4 bnc[CIN];                                       // 1024 B

    int tid = threadIdx.x;
    int lane = tid & 63, wave = tid >> 6;
    int b = blockIdx.y, bx = blockIdx.x;
    int l0base = bx * (64 * NT);

    if (tid < CIN) {
        // bit-exact vs np fp32: gamma / sqrt(var + eps)
        float s = __fdiv_rn(bn_g[tid], __fsqrt_rn(__fadd_rn(bn_v[tid], 1e-5f)));
        bnc[tid] = make_float4(s, bn_m[tid], bn_b[tid], 0.f);
    }

    const float* Ib = I + (size_t)b * CIN * LEN;

    // DMA plan: slot s = wave*5+i covers chunks n = s*64+lane; chunk n = ci*20+c
    // lands at raw float index n*4 = ci*80 + 4c; global p = l0-8+4c+(0..3).
    const char* gb[5]; int cb[5];
    #pragma unroll
    for (int i = 0; i < 5; ++i) {
        int n = (wave * 5 + i) * 64 + lane;
        int ci = n / 20;
        int c  = n - 20 * ci;
        cb[i] = 16 * c - 32;                                  // byte offset before +4*l0
        gb[i] = (const char*)(Ib + (size_t)ci * LEN) + cb[i];
    }

    {   // DMA tile 0
        int l4 = 4 * l0base;
        #pragma unroll
        for (int i = 0; i < 5; ++i) {
            int off = cb[i] + l4;
            if (off >= 0 && off + 16 <= LEN * 4)
                __builtin_amdgcn_global_load_lds((gp1_t)(gb[i] + l4),
                                                 (lp3_t)(raw + (wave * 5 + i) * 256), 16, 0, 0);
        }
    }
    __syncthreads();   // bnc visible + DMA(0) drained (vmcnt(0) at barrier)

    int g8 = tid >> 5, rb = tid & 31;
    float sc[8], mu[8], be[8];
    #pragma unroll
    for (int j = 0; j < 8; ++j) {
        float4 cc = bnc[8 * g8 + j];
        sc[j] = cc.x; mu[j] = cc.y; be[j] = cc.z;
    }

    int quad = lane >> 4, lr = lane & 15;
    int cout0 = wave * 32;
    const ushort* wbase = Wt + ((size_t)cout0 + lr) * CIN + quad * 8;
    float pw  = prelu[0];
    float al0 = alpha[cout0 + lr];
    float al1 = alpha[cout0 + 16 + lr];
    float* obase = out + ((size_t)b * COUT) * LPOOL + bx * (32 * NT);

    for (int t = 0; t < NT; ++t) {
        int l0 = l0base + t * 64;

        // ---- binarize raw -> stg (LDS->LDS, conflict-free both sides) ----
        #pragma unroll
        for (int it = 0; it < 3; ++it) {
            int r = rb + 32 * it;
            if (r < RROWS) {
                int p = l0 - 4 + r;
                bool pok = (p >= 0) && (p < LEN);
                v8us u;
                #pragma unroll
                for (int j = 0; j < 8; ++j) {
                    float v = raw[(8 * g8 + j) * RAWP + r + 4];
                    // (v - mean) * scale + beta, exact np rounding (sign boundary)
                    float x = __fadd_rn(__fmul_rn(__fsub_rn(v, mu[j]), sc[j]), be[j]);
                    ushort s = x > 0.f ? (ushort)0x3F80 : (x < 0.f ? (ushort)0xBF80 : (ushort)0);
                    u[j] = pok ? s : (ushort)0;
                }
                *(v8us*)(&stg[r * 72 + g8 * 8]) = u;
            }
        }
        __syncthreads();   // stg visible; raw free for next DMA

        if (t + 1 < NT) {  // DMA(t+1) flies under MFMA(t)
            int l4 = 4 * (l0 + 64);
            #pragma unroll
            for (int i = 0; i < 5; ++i) {
                int off = cb[i] + l4;
                if (off >= 0 && off + 16 <= LEN * 4)
                    __builtin_amdgcn_global_load_lds((gp1_t)(gb[i] + l4),
                                                     (lp3_t)(raw + (wave * 5 + i) * 256), 16, 0, 0);
            }
        }

        // ---- MFMA(t) ----
        v4f acc[4][2];
        #pragma unroll
        for (int mt = 0; mt < 4; ++mt) { acc[mt][0] = (v4f)0.f; acc[mt][1] = (v4f)0.f; }

        #pragma unroll
        for (int k = 0; k < KW; ++k) {
            const ushort* wk = wbase + (size_t)k * COUT * CIN;
            #pragma unroll
            for (int h = 0; h < 2; ++h) {
                int cibase = h * 32 + quad * 8;
                v8bf b0 = *(const v8bf*)(wk + h * 32);
                v8bf b1 = *(const v8bf*)(wk + h * 32 + 16 * CIN);
                #pragma unroll
                for (int mt = 0; mt < 4; ++mt) {
                    // A row for output l=mt*16+lr at tap k: r = l + k + 1
                    v8bf a = *(const v8bf*)(&stg[(mt * 16 + lr + k + 1) * 72 + cibase]);
                    acc[mt][0] = __builtin_amdgcn_mfma_f32_16x16x32_bf16(a, b0, acc[mt][0], 0, 0, 0);
                    acc[mt][1] = __builtin_amdgcn_mfma_f32_16x16x32_bf16(a, b1, acc[mt][1], 0, 0, 0);
                }
            }
        }

        // ---- epilogue(t): alpha * PReLU, in-lane pool, float2 stores ----
        float* ob = obase + t * 32;
        #pragma unroll
        for (int n2 = 0; n2 < 2; ++n2) {
            float al = n2 ? al1 : al0;
            int co = cout0 + n2 * 16 + lr;
            float* oc = ob + (size_t)co * LPOOL + quad * 2;
            #pragma unroll
            for (int mt = 0; mt < 4; ++mt) {
                float v0 = acc[mt][n2][0] * al; v0 = v0 > 0.f ? v0 : pw * v0;
                float v1 = acc[mt][n2][1] * al; v1 = v1 > 0.f ? v1 : pw * v1;
                float v2 = acc[mt][n2][2] * al; v2 = v2 > 0.f ? v2 : pw * v2;
                float v3 = acc[mt][n2][3] * al; v3 = v3 > 0.f ? v3 : pw * v3;
                *(float2*)(oc + mt * 8) = make_float2(fmaxf(v0, v1), fmaxf(v2, v3));
            }
        }
        __syncthreads();   // drains DMA(t+1); protects stg until MFMA done
    }
}

extern "C" void kernel_launch(void* const* d_in, const int* in_sizes, int n_in,
                              void* d_out, int out_size, void* d_ws, size_t ws_size,
                              hipStream_t stream) {
    const float* I      = (const float*)d_in[0];
    const float* bn_g   = (const float*)d_in[1];
    const float* bn_b   = (const float*)d_in[2];
    const float* bn_m   = (const float*)d_in[3];
    const float* bn_v   = (const float*)d_in[4];
    const float* conv_w = (const float*)d_in[5];
    const float* alpha  = (const float*)d_in[6];
    const float* prelu  = (const float*)d_in[7];
    float* out = (float*)d_out;

    ushort* Wt = (ushort*)d_ws;   // 7*128*64*2 = 114688 bytes

    wconv_kernel<<<(COUT * CIN * KW + 255) / 256, 256, 0, stream>>>(conv_w, Wt);
    dim3 grid(LEN / (64 * NT), BATCH);
    conv_kernel<<<grid, 256, 0, stream>>>(I, bn_g, bn_b, bn_m, bn_v, Wt, alpha, prelu, out);
}

// Round 5
// 217.013 us; speedup vs baseline: 1.3073x; 1.3073x over previous
//
#include <hip/hip_runtime.h>
#include <hip/hip_bf16.h>
#include <stdint.h>

#define BATCH 64
#define CIN   64
#define LEN   4096
#define COUT  128
#define KW    7
#define LPOOL 2048
#define NT    4     // l sub-tiles of 64 per block
#define RROWS 72    // sign rows: p = l0-4+r, r in [0,72)
#define RAWP  80    // raw floats per ci row: p = l0-8+col, col in [0,80)

typedef __bf16 v8bf __attribute__((ext_vector_type(8)));
typedef unsigned short v8us __attribute__((ext_vector_type(8)));
typedef float  v4f  __attribute__((ext_vector_type(4)));

typedef const __attribute__((address_space(1))) void* gp1_t;
typedef __attribute__((address_space(3))) void* lp3_t;

// Convert conv_w [COUT][CIN][KW] fp32 -> Wt [KW][COUT][CIN] bf16 (RNE).
__global__ __launch_bounds__(256)
void wconv_kernel(const float* __restrict__ W, ushort* __restrict__ Wt) {
    int i = blockIdx.x * 256 + threadIdx.x;
    if (i >= COUT * CIN * KW) return;
    int co  = i / (CIN * KW);
    int rem = i - co * (CIN * KW);
    int ci  = rem / KW;
    int k   = rem - ci * KW;
    uint u = __float_as_uint(W[i]);
    uint r = (u + 0x7FFFu + ((u >> 16) & 1u)) >> 16;   // RNE to bf16
    Wt[(k * COUT + co) * CIN + ci] = (ushort)r;
}

// Fused: BN -> sign -> conv (bf16 MFMA) -> alpha -> PReLU -> maxpool2.
// Block: 256 threads, NT=4 l-sub-tiles. global_load_lds DMA staging (zero
// VGPR cost). Register-pressure discipline (anti-spill, cf. R3/R4):
//   - BN constants read from LDS inside binarize only (no long-lived arrays)
//   - weights in an explicit 2-deep wcur/wnxt chain (32 regs max in flight)
// Pipeline/tile: binarize(t) | barrier | DMA(t+1) | MFMA(t)+stores | barrier.
__global__ __launch_bounds__(256, 4)
void conv_kernel(const float* __restrict__ I,
                 const float* __restrict__ bn_g, const float* __restrict__ bn_b,
                 const float* __restrict__ bn_m, const float* __restrict__ bn_v,
                 const ushort* __restrict__ Wt,
                 const float* __restrict__ alpha, const float* __restrict__ prelu,
                 float* __restrict__ out) {
    __shared__ __attribute__((aligned(16))) float  raw[CIN * RAWP];   // 20480 B
    __shared__ __attribute__((aligned(16))) ushort stg[RROWS * 72];   // 10368 B, pitch 144B
    __shared__ float4 bnc[CIN];                                       // 1024 B

    int tid = threadIdx.x;
    int lane = tid & 63, wave = tid >> 6;
    int b = blockIdx.y, bx = blockIdx.x;
    int l0base = bx * (64 * NT);

    if (tid < CIN) {
        // bit-exact vs np fp32: gamma / sqrt(var + eps)
        float s = __fdiv_rn(bn_g[tid], __fsqrt_rn(__fadd_rn(bn_v[tid], 1e-5f)));
        bnc[tid] = make_float4(s, bn_m[tid], bn_b[tid], 0.f);
    }

    const float* Ib = I + (size_t)b * CIN * LEN;

    // DMA plan: slot s = wave*5+i covers chunks n = s*64+lane; chunk n = ci*20+c
    // lands at raw float index n*4 = ci*80 + 4c; global p = l0-8+4c+(0..3).
    const char* gb[5]; int cb[5];
    #pragma unroll
    for (int i = 0; i < 5; ++i) {
        int n = (wave * 5 + i) * 64 + lane;
        int ci = n / 20;
        int c  = n - 20 * ci;
        cb[i] = 16 * c - 32;                                  // byte offset before +4*l0
        gb[i] = (const char*)(Ib + (size_t)ci * LEN) + cb[i];
    }

    {   // DMA tile 0
        int l4 = 4 * l0base;
        #pragma unroll
        for (int i = 0; i < 5; ++i) {
            int off = cb[i] + l4;
            if (off >= 0 && off + 16 <= LEN * 4)
                __builtin_amdgcn_global_load_lds((gp1_t)(gb[i] + l4),
                                                 (lp3_t)(raw + (wave * 5 + i) * 256), 16, 0, 0);
        }
    }
    __syncthreads();   // bnc visible + DMA(0) drained (vmcnt(0) at barrier)

    int g8 = tid >> 5, rb = tid & 31;
    int quad = lane >> 4, lr = lane & 15;
    int cout0 = wave * 32;
    const ushort* wbase = Wt + ((size_t)cout0 + lr) * CIN + quad * 8;
    float pw  = prelu[0];
    float al0 = alpha[cout0 + lr];
    float al1 = alpha[cout0 + 16 + lr];
    float* obase = out + ((size_t)b * COUT) * LPOOL + bx * (32 * NT);

    for (int t = 0; t < NT; ++t) {
        int l0 = l0base + t * 64;

        // ---- binarize raw -> stg (BN consts from LDS: short live ranges) ----
        #pragma unroll
        for (int it = 0; it < 3; ++it) {
            int r = rb + 32 * it;
            if (r < RROWS) {
                int p = l0 - 4 + r;
                bool pok = (p >= 0) && (p < LEN);
                v8us u;
                #pragma unroll
                for (int j = 0; j < 8; ++j) {
                    float4 cc = bnc[8 * g8 + j];
                    float v = raw[(8 * g8 + j) * RAWP + r + 4];
                    // (v - mean) * scale + beta, exact np rounding (sign boundary)
                    float x = __fadd_rn(__fmul_rn(__fsub_rn(v, cc.y), cc.x), cc.z);
                    ushort s = x > 0.f ? (ushort)0x3F80 : (x < 0.f ? (ushort)0xBF80 : (ushort)0);
                    u[j] = pok ? s : (ushort)0;
                }
                *(v8us*)(&stg[r * 72 + g8 * 8]) = u;
            }
        }
        __syncthreads();   // stg visible; raw free for next DMA

        if (t + 1 < NT) {  // DMA(t+1) flies under MFMA(t)
            int l4 = 4 * (l0 + 64);
            #pragma unroll
            for (int i = 0; i < 5; ++i) {
                int off = cb[i] + l4;
                if (off >= 0 && off + 16 <= LEN * 4)
                    __builtin_amdgcn_global_load_lds((gp1_t)(gb[i] + l4),
                                                     (lp3_t)(raw + (wave * 5 + i) * 256), 16, 0, 0);
            }
        }

        // ---- MFMA(t): explicit 2-deep weight chain (caps pressure at 32) ----
        v4f acc[4][2];
        #pragma unroll
        for (int mt = 0; mt < 4; ++mt) { acc[mt][0] = (v4f)0.f; acc[mt][1] = (v4f)0.f; }

        v8bf wcur[2][2], wnxt[2][2];
        #pragma unroll
        for (int h = 0; h < 2; ++h)
            #pragma unroll
            for (int n2 = 0; n2 < 2; ++n2)
                wcur[h][n2] = *(const v8bf*)(wbase + h * 32 + n2 * 16 * CIN);

        #pragma unroll
        for (int k = 0; k < KW; ++k) {
            if (k + 1 < KW) {
                const ushort* wk = wbase + (size_t)(k + 1) * COUT * CIN;
                #pragma unroll
                for (int h = 0; h < 2; ++h)
                    #pragma unroll
                    for (int n2 = 0; n2 < 2; ++n2)
                        wnxt[h][n2] = *(const v8bf*)(wk + h * 32 + n2 * 16 * CIN);
            }
            #pragma unroll
            for (int h = 0; h < 2; ++h) {
                int cibase = h * 32 + quad * 8;
                #pragma unroll
                for (int mt = 0; mt < 4; ++mt) {
                    // A row for output l=mt*16+lr at tap k: r = l + k + 1
                    v8bf a = *(const v8bf*)(&stg[(mt * 16 + lr + k + 1) * 72 + cibase]);
                    acc[mt][0] = __builtin_amdgcn_mfma_f32_16x16x32_bf16(a, wcur[h][0], acc[mt][0], 0, 0, 0);
                    acc[mt][1] = __builtin_amdgcn_mfma_f32_16x16x32_bf16(a, wcur[h][1], acc[mt][1], 0, 0, 0);
                }
            }
            #pragma unroll
            for (int h = 0; h < 2; ++h)
                #pragma unroll
                for (int n2 = 0; n2 < 2; ++n2)
                    wcur[h][n2] = wnxt[h][n2];
        }

        // ---- epilogue(t): alpha * PReLU, in-lane pool, float2 stores ----
        float* ob = obase + t * 32;
        #pragma unroll
        for (int n2 = 0; n2 < 2; ++n2) {
            float al = n2 ? al1 : al0;
            int co = cout0 + n2 * 16 + lr;
            float* oc = ob + (size_t)co * LPOOL + quad * 2;
            #pragma unroll
            for (int mt = 0; mt < 4; ++mt) {
                float v0 = acc[mt][n2][0] * al; v0 = v0 > 0.f ? v0 : pw * v0;
                float v1 = acc[mt][n2][1] * al; v1 = v1 > 0.f ? v1 : pw * v1;
                float v2 = acc[mt][n2][2] * al; v2 = v2 > 0.f ? v2 : pw * v2;
                float v3 = acc[mt][n2][3] * al; v3 = v3 > 0.f ? v3 : pw * v3;
                *(float2*)(oc + mt * 8) = make_float2(fmaxf(v0, v1), fmaxf(v2, v3));
            }
        }
        __syncthreads();   // drains DMA(t+1); protects stg until MFMA done
    }
}

extern "C" void kernel_launch(void* const* d_in, const int* in_sizes, int n_in,
                              void* d_out, int out_size, void* d_ws, size_t ws_size,
                              hipStream_t stream) {
    const float* I      = (const float*)d_in[0];
    const float* bn_g   = (const float*)d_in[1];
    const float* bn_b   = (const float*)d_in[2];
    const float* bn_m   = (const float*)d_in[3];
    const float* bn_v   = (const float*)d_in[4];
    const float* conv_w = (const float*)d_in[5];
    const float* alpha  = (const float*)d_in[6];
    const float* prelu  = (const float*)d_in[7];
    float* out = (float*)d_out;

    ushort* Wt = (ushort*)d_ws;   // 7*128*64*2 = 114688 bytes

    wconv_kernel<<<(COUT * CIN * KW + 255) / 256, 256, 0, stream>>>(conv_w, Wt);
    dim3 grid(LEN / (64 * NT), BATCH);
    conv_kernel<<<grid, 256, 0, stream>>>(I, bn_g, bn_b, bn_m, bn_v, Wt, alpha, prelu, out);
}

// Round 6
// 211.937 us; speedup vs baseline: 1.3386x; 1.0239x over previous
//
#include <hip/hip_runtime.h>
#include <hip/hip_bf16.h>
#include <stdint.h>

#define BATCH 64
#define CIN   64
#define LEN   4096
#define COUT  128
#define KW    7
#define LPOOL 2048
#define NT    4     // l sub-tiles of 64 per block
#define RROWS 72    // sign rows: p = l0-4+r, r in [0,72)
#define RAWP  80    // raw floats per ci row: p = l0-8+col, col in [0,80)

typedef __bf16 v8bf __attribute__((ext_vector_type(8)));
typedef unsigned short v8us __attribute__((ext_vector_type(8)));
typedef float  v4f  __attribute__((ext_vector_type(4)));

typedef const __attribute__((address_space(1))) void* gp1_t;
typedef __attribute__((address_space(3))) void* lp3_t;

// Convert conv_w [COUT][CIN][KW] fp32 -> Wt [KW][COUT][CIN] bf16 (RNE).
__global__ __launch_bounds__(256)
void wconv_kernel(const float* __restrict__ W, ushort* __restrict__ Wt) {
    int i = blockIdx.x * 256 + threadIdx.x;
    if (i >= COUT * CIN * KW) return;
    int co  = i / (CIN * KW);
    int rem = i - co * (CIN * KW);
    int ci  = rem / KW;
    int k   = rem - ci * KW;
    uint u = __float_as_uint(W[i]);
    uint r = (u + 0x7FFFu + ((u >> 16) & 1u)) >> 16;   // RNE to bf16
    Wt[(k * COUT + co) * CIN + ci] = (ushort)r;
}

// Fused: BN -> sign -> conv (bf16 MFMA) -> alpha -> PReLU -> maxpool2.
// Block: 256 threads, NT=4 l-sub-tiles. global_load_lds DMA staging (zero
// VGPR cost). launch_bounds(256,3): cap ~170 VGPRs -- reg demand ~140; the
// (256,4)/128-reg cap caused persistent scratch spills (R3/R4/R5 all showed
// ~70-165MB/dir excess HBM traffic = the binding constraint). Measured
// occupancy was ~3 blocks/CU in every round anyway.
// Pipeline/tile: binarize(t) | barrier | DMA(t+1) | MFMA(t)+stores | barrier.
__global__ __launch_bounds__(256, 3)
void conv_kernel(const float* __restrict__ I,
                 const float* __restrict__ bn_g, const float* __restrict__ bn_b,
                 const float* __restrict__ bn_m, const float* __restrict__ bn_v,
                 const ushort* __restrict__ Wt,
                 const float* __restrict__ alpha, const float* __restrict__ prelu,
                 float* __restrict__ out) {
    __shared__ __attribute__((aligned(16))) float  raw[CIN * RAWP];   // 20480 B
    __shared__ __attribute__((aligned(16))) ushort stg[RROWS * 72];   // 10368 B, pitch 144B
    __shared__ float4 bnc[CIN];                                       // 1024 B

    int tid = threadIdx.x;
    int lane = tid & 63, wave = tid >> 6;
    int b = blockIdx.y, bx = blockIdx.x;
    int l0base = bx * (64 * NT);

    if (tid < CIN) {
        // bit-exact vs np fp32: gamma / sqrt(var + eps)
        float s = __fdiv_rn(bn_g[tid], __fsqrt_rn(__fadd_rn(bn_v[tid], 1e-5f)));
        bnc[tid] = make_float4(s, bn_m[tid], bn_b[tid], 0.f);
    }

    const float* Ib = I + (size_t)b * CIN * LEN;

    // DMA plan: slot s = wave*5+i covers chunks n = s*64+lane; chunk n = ci*20+c
    // lands at raw float index n*4 = ci*80 + 4c; global p = l0-8+4c+(0..3).
    const char* gb[5]; int cb[5];
    #pragma unroll
    for (int i = 0; i < 5; ++i) {
        int n = (wave * 5 + i) * 64 + lane;
        int ci = n / 20;
        int c  = n - 20 * ci;
        cb[i] = 16 * c - 32;                                  // byte offset before +4*l0
        gb[i] = (const char*)(Ib + (size_t)ci * LEN) + cb[i];
    }

    {   // DMA tile 0
        int l4 = 4 * l0base;
        #pragma unroll
        for (int i = 0; i < 5; ++i) {
            int off = cb[i] + l4;
            if (off >= 0 && off + 16 <= LEN * 4)
                __builtin_amdgcn_global_load_lds((gp1_t)(gb[i] + l4),
                                                 (lp3_t)(raw + (wave * 5 + i) * 256), 16, 0, 0);
        }
    }
    __syncthreads();   // bnc visible + DMA(0) drained (vmcnt(0) at barrier)

    int g8 = tid >> 5, rb = tid & 31;
    int quad = lane >> 4, lr = lane & 15;
    int cout0 = wave * 32;
    const ushort* wbase = Wt + ((size_t)cout0 + lr) * CIN + quad * 8;
    float pw  = prelu[0];
    float al0 = alpha[cout0 + lr];
    float al1 = alpha[cout0 + 16 + lr];
    float* obase = out + ((size_t)b * COUT) * LPOOL + bx * (32 * NT);

    for (int t = 0; t < NT; ++t) {
        int l0 = l0base + t * 64;

        // ---- binarize raw -> stg (BN consts from LDS: short live ranges) ----
        #pragma unroll
        for (int it = 0; it < 3; ++it) {
            int r = rb + 32 * it;
            if (r < RROWS) {
                int p = l0 - 4 + r;
                bool pok = (p >= 0) && (p < LEN);
                v8us u;
                #pragma unroll
                for (int j = 0; j < 8; ++j) {
                    float4 cc = bnc[8 * g8 + j];
                    float v = raw[(8 * g8 + j) * RAWP + r + 4];
                    // (v - mean) * scale + beta, exact np rounding (sign boundary)
                    float x = __fadd_rn(__fmul_rn(__fsub_rn(v, cc.y), cc.x), cc.z);
                    ushort s = x > 0.f ? (ushort)0x3F80 : (x < 0.f ? (ushort)0xBF80 : (ushort)0);
                    u[j] = pok ? s : (ushort)0;
                }
                *(v8us*)(&stg[r * 72 + g8 * 8]) = u;
            }
        }
        __syncthreads();   // stg visible; raw free for next DMA

        if (t + 1 < NT) {  // DMA(t+1) flies under MFMA(t)
            int l4 = 4 * (l0 + 64);
            #pragma unroll
            for (int i = 0; i < 5; ++i) {
                int off = cb[i] + l4;
                if (off >= 0 && off + 16 <= LEN * 4)
                    __builtin_amdgcn_global_load_lds((gp1_t)(gb[i] + l4),
                                                     (lp3_t)(raw + (wave * 5 + i) * 256), 16, 0, 0);
            }
        }

        // ---- MFMA(t): explicit 2-deep weight chain (caps pressure at 32) ----
        v4f acc[4][2];
        #pragma unroll
        for (int mt = 0; mt < 4; ++mt) { acc[mt][0] = (v4f)0.f; acc[mt][1] = (v4f)0.f; }

        v8bf wcur[2][2], wnxt[2][2];
        #pragma unroll
        for (int h = 0; h < 2; ++h)
            #pragma unroll
            for (int n2 = 0; n2 < 2; ++n2)
                wcur[h][n2] = *(const v8bf*)(wbase + h * 32 + n2 * 16 * CIN);

        #pragma unroll
        for (int k = 0; k < KW; ++k) {
            if (k + 1 < KW) {
                const ushort* wk = wbase + (size_t)(k + 1) * COUT * CIN;
                #pragma unroll
                for (int h = 0; h < 2; ++h)
                    #pragma unroll
                    for (int n2 = 0; n2 < 2; ++n2)
                        wnxt[h][n2] = *(const v8bf*)(wk + h * 32 + n2 * 16 * CIN);
            }
            #pragma unroll
            for (int h = 0; h < 2; ++h) {
                int cibase = h * 32 + quad * 8;
                #pragma unroll
                for (int mt = 0; mt < 4; ++mt) {
                    // A row for output l=mt*16+lr at tap k: r = l + k + 1
                    v8bf a = *(const v8bf*)(&stg[(mt * 16 + lr + k + 1) * 72 + cibase]);
                    acc[mt][0] = __builtin_amdgcn_mfma_f32_16x16x32_bf16(a, wcur[h][0], acc[mt][0], 0, 0, 0);
                    acc[mt][1] = __builtin_amdgcn_mfma_f32_16x16x32_bf16(a, wcur[h][1], acc[mt][1], 0, 0, 0);
                }
            }
            #pragma unroll
            for (int h = 0; h < 2; ++h)
                #pragma unroll
                for (int n2 = 0; n2 < 2; ++n2)
                    wcur[h][n2] = wnxt[h][n2];
        }

        // ---- epilogue(t): alpha * PReLU, in-lane pool, float2 stores ----
        float* ob = obase + t * 32;
        #pragma unroll
        for (int n2 = 0; n2 < 2; ++n2) {
            float al = n2 ? al1 : al0;
            int co = cout0 + n2 * 16 + lr;
            float* oc = ob + (size_t)co * LPOOL + quad * 2;
            #pragma unroll
            for (int mt = 0; mt < 4; ++mt) {
                float v0 = acc[mt][n2][0] * al; v0 = v0 > 0.f ? v0 : pw * v0;
                float v1 = acc[mt][n2][1] * al; v1 = v1 > 0.f ? v1 : pw * v1;
                float v2 = acc[mt][n2][2] * al; v2 = v2 > 0.f ? v2 : pw * v2;
                float v3 = acc[mt][n2][3] * al; v3 = v3 > 0.f ? v3 : pw * v3;
                *(float2*)(oc + mt * 8) = make_float2(fmaxf(v0, v1), fmaxf(v2, v3));
            }
        }
        __syncthreads();   // drains DMA(t+1); protects stg until MFMA done
    }
}

extern "C" void kernel_launch(void* const* d_in, const int* in_sizes, int n_in,
                              void* d_out, int out_size, void* d_ws, size_t ws_size,
                              hipStream_t stream) {
    const float* I      = (const float*)d_in[0];
    const float* bn_g   = (const float*)d_in[1];
    const float* bn_b   = (const float*)d_in[2];
    const float* bn_m   = (const float*)d_in[3];
    const float* bn_v   = (const float*)d_in[4];
    const float* conv_w = (const float*)d_in[5];
    const float* alpha  = (const float*)d_in[6];
    const float* prelu  = (const float*)d_in[7];
    float* out = (float*)d_out;

    ushort* Wt = (ushort*)d_ws;   // 7*128*64*2 = 114688 bytes

    wconv_kernel<<<(COUT * CIN * KW + 255) / 256, 256, 0, stream>>>(conv_w, Wt);
    dim3 grid(LEN / (64 * NT), BATCH);
    conv_kernel<<<grid, 256, 0, stream>>>(I, bn_g, bn_b, bn_m, bn_v, Wt, alpha, prelu, out);
}

// Round 7
// 176.860 us; speedup vs baseline: 1.6040x; 1.1983x over previous
//
#include <hip/hip_runtime.h>
#include <hip/hip_bf16.h>
#include <stdint.h>

#define BATCH 64
#define CIN   64
#define LEN   4096
#define COUT  128
#define KW    7
#define LPOOL 2048
#define NT    4     // l sub-tiles of 64 per block
#define RROWS 72    // sign rows: p = l0-4+r, r in [0,72)
#define RAWP  80    // raw floats per ci row: p = l0-8+col, col in [0,80)

typedef __bf16 v8bf __attribute__((ext_vector_type(8)));
typedef unsigned short v8us __attribute__((ext_vector_type(8)));
typedef float  v4f  __attribute__((ext_vector_type(4)));

typedef const __attribute__((address_space(1))) void* gp1_t;
typedef __attribute__((address_space(3))) void* lp3_t;

// Convert conv_w [COUT][CIN][KW] fp32 -> Wt [KW][COUT][CIN] bf16 (RNE).
__global__ __launch_bounds__(256)
void wconv_kernel(const float* __restrict__ W, ushort* __restrict__ Wt) {
    int i = blockIdx.x * 256 + threadIdx.x;
    if (i >= COUT * CIN * KW) return;
    int co  = i / (CIN * KW);
    int rem = i - co * (CIN * KW);
    int ci  = rem / KW;
    int k   = rem - ci * KW;
    uint u = __float_as_uint(W[i]);
    uint r = (u + 0x7FFFu + ((u >> 16) & 1u)) >> 16;   // RNE to bf16
    Wt[(k * COUT + co) * CIN + ci] = (ushort)r;
}

// Fused: BN -> sign -> conv (bf16 MFMA) -> alpha -> PReLU -> maxpool2.
// Block: 256 threads, NT=4 l-sub-tiles. global_load_lds DMA staging.
// Register-pressure root cause (R3-R6): fully-unrolled k-loop let the
// scheduler batch up to 56 ds_read_b128 A-frags (~224 regs wanted) ->
// persistent scratch spills at ANY launch-bounds cap. Fix: k-loop is
// #pragma unroll 1 (per-iter in-flight ~105 regs), back to (256,4).
// Pipeline/tile: binarize(t) | barrier | DMA(t+1) | MFMA(t)+stores | barrier.
__global__ __launch_bounds__(256, 4)
void conv_kernel(const float* __restrict__ I,
                 const float* __restrict__ bn_g, const float* __restrict__ bn_b,
                 const float* __restrict__ bn_m, const float* __restrict__ bn_v,
                 const ushort* __restrict__ Wt,
                 const float* __restrict__ alpha, const float* __restrict__ prelu,
                 float* __restrict__ out) {
    __shared__ __attribute__((aligned(16))) float  raw[CIN * RAWP];   // 20480 B
    __shared__ __attribute__((aligned(16))) ushort stg[RROWS * 72];   // 10368 B, pitch 144B
    __shared__ float4 bnc[CIN];                                       // 1024 B

    int tid = threadIdx.x;
    int lane = tid & 63, wave = tid >> 6;
    int b = blockIdx.y, bx = blockIdx.x;
    int l0base = bx * (64 * NT);

    if (tid < CIN) {
        // bit-exact vs np fp32: gamma / sqrt(var + eps)
        float s = __fdiv_rn(bn_g[tid], __fsqrt_rn(__fadd_rn(bn_v[tid], 1e-5f)));
        bnc[tid] = make_float4(s, bn_m[tid], bn_b[tid], 0.f);
    }

    const float* Ib = I + (size_t)b * CIN * LEN;

    // DMA plan: slot s = wave*5+i covers chunks n = s*64+lane; chunk n = ci*20+c
    // lands at raw float index n*4 = ci*80 + 4c; global p = l0-8+4c+(0..3).
    const char* gb[5]; int cb[5];
    #pragma unroll
    for (int i = 0; i < 5; ++i) {
        int n = (wave * 5 + i) * 64 + lane;
        int ci = n / 20;
        int c  = n - 20 * ci;
        cb[i] = 16 * c - 32;                                  // byte offset before +4*l0
        gb[i] = (const char*)(Ib + (size_t)ci * LEN) + cb[i];
    }

    {   // DMA tile 0
        int l4 = 4 * l0base;
        #pragma unroll
        for (int i = 0; i < 5; ++i) {
            int off = cb[i] + l4;
            if (off >= 0 && off + 16 <= LEN * 4)
                __builtin_amdgcn_global_load_lds((gp1_t)(gb[i] + l4),
                                                 (lp3_t)(raw + (wave * 5 + i) * 256), 16, 0, 0);
        }
    }
    __syncthreads();   // bnc visible + DMA(0) drained (vmcnt(0) at barrier)

    int g8 = tid >> 5, rb = tid & 31;
    int quad = lane >> 4, lr = lane & 15;
    int cout0 = wave * 32;
    const ushort* wbase = Wt + ((size_t)cout0 + lr) * CIN + quad * 8;
    float pw  = prelu[0];
    float al0 = alpha[cout0 + lr];
    float al1 = alpha[cout0 + 16 + lr];
    float* obase = out + ((size_t)b * COUT) * LPOOL + bx * (32 * NT);

    for (int t = 0; t < NT; ++t) {
        int l0 = l0base + t * 64;

        // ---- binarize raw -> stg (BN consts from LDS: short live ranges) ----
        #pragma unroll
        for (int it = 0; it < 3; ++it) {
            int r = rb + 32 * it;
            if (r < RROWS) {
                int p = l0 - 4 + r;
                bool pok = (p >= 0) && (p < LEN);
                v8us u;
                #pragma unroll
                for (int j = 0; j < 8; ++j) {
                    float4 cc = bnc[8 * g8 + j];
                    float v = raw[(8 * g8 + j) * RAWP + r + 4];
                    // (v - mean) * scale + beta, exact np rounding (sign boundary)
                    float x = __fadd_rn(__fmul_rn(__fsub_rn(v, cc.y), cc.x), cc.z);
                    ushort s = x > 0.f ? (ushort)0x3F80 : (x < 0.f ? (ushort)0xBF80 : (ushort)0);
                    u[j] = pok ? s : (ushort)0;
                }
                *(v8us*)(&stg[r * 72 + g8 * 8]) = u;
            }
        }
        __syncthreads();   // stg visible; raw free for next DMA

        if (t + 1 < NT) {  // DMA(t+1) flies under MFMA(t)
            int l4 = 4 * (l0 + 64);
            #pragma unroll
            for (int i = 0; i < 5; ++i) {
                int off = cb[i] + l4;
                if (off >= 0 && off + 16 <= LEN * 4)
                    __builtin_amdgcn_global_load_lds((gp1_t)(gb[i] + l4),
                                                     (lp3_t)(raw + (wave * 5 + i) * 256), 16, 0, 0);
            }
        }

        // ---- MFMA(t): k-loop NOT unrolled (caps reg demand ~105) ----
        v4f acc[4][2];
        #pragma unroll
        for (int mt = 0; mt < 4; ++mt) { acc[mt][0] = (v4f)0.f; acc[mt][1] = (v4f)0.f; }

        const ushort* wk   = wbase;
        const ushort* arow = &stg[(lr + 1) * 72 + quad * 8];
        #pragma unroll 1
        for (int k = 0; k < KW; ++k) {
            v8bf w00 = *(const v8bf*)(wk);                  // h=0, n2=0
            v8bf w01 = *(const v8bf*)(wk + 16 * CIN);       // h=0, n2=1
            v8bf w10 = *(const v8bf*)(wk + 32);             // h=1, n2=0
            v8bf w11 = *(const v8bf*)(wk + 32 + 16 * CIN);  // h=1, n2=1
            #pragma unroll
            for (int mt = 0; mt < 4; ++mt) {
                // A row for output l=mt*16+lr at tap k: r = l + k + 1
                v8bf a0 = *(const v8bf*)(arow + mt * 16 * 72);        // ci 0..31 slice
                v8bf a1 = *(const v8bf*)(arow + mt * 16 * 72 + 32);   // ci 32..63 slice
                acc[mt][0] = __builtin_amdgcn_mfma_f32_16x16x32_bf16(a0, w00, acc[mt][0], 0, 0, 0);
                acc[mt][1] = __builtin_amdgcn_mfma_f32_16x16x32_bf16(a0, w01, acc[mt][1], 0, 0, 0);
                acc[mt][0] = __builtin_amdgcn_mfma_f32_16x16x32_bf16(a1, w10, acc[mt][0], 0, 0, 0);
                acc[mt][1] = __builtin_amdgcn_mfma_f32_16x16x32_bf16(a1, w11, acc[mt][1], 0, 0, 0);
            }
            wk   += COUT * CIN;   // next tap's weight plane
            arow += 72;           // next tap shifts A window by one row
        }

        // ---- epilogue(t): alpha * PReLU, in-lane pool, float2 stores ----
        float* ob = obase + t * 32;
        #pragma unroll
        for (int n2 = 0; n2 < 2; ++n2) {
            float al = n2 ? al1 : al0;
            int co = cout0 + n2 * 16 + lr;
            float* oc = ob + (size_t)co * LPOOL + quad * 2;
            #pragma unroll
            for (int mt = 0; mt < 4; ++mt) {
                float v0 = acc[mt][n2][0] * al; v0 = v0 > 0.f ? v0 : pw * v0;
                float v1 = acc[mt][n2][1] * al; v1 = v1 > 0.f ? v1 : pw * v1;
                float v2 = acc[mt][n2][2] * al; v2 = v2 > 0.f ? v2 : pw * v2;
                float v3 = acc[mt][n2][3] * al; v3 = v3 > 0.f ? v3 : pw * v3;
                *(float2*)(oc + mt * 8) = make_float2(fmaxf(v0, v1), fmaxf(v2, v3));
            }
        }
        __syncthreads();   // drains DMA(t+1); protects stg until MFMA done
    }
}

extern "C" void kernel_launch(void* const* d_in, const int* in_sizes, int n_in,
                              void* d_out, int out_size, void* d_ws, size_t ws_size,
                              hipStream_t stream) {
    const float* I      = (const float*)d_in[0];
    const float* bn_g   = (const float*)d_in[1];
    const float* bn_b   = (const float*)d_in[2];
    const float* bn_m   = (const float*)d_in[3];
    const float* bn_v   = (const float*)d_in[4];
    const float* conv_w = (const float*)d_in[5];
    const float* alpha  = (const float*)d_in[6];
    const float* prelu  = (const float*)d_in[7];
    float* out = (float*)d_out;

    ushort* Wt = (ushort*)d_ws;   // 7*128*64*2 = 114688 bytes

    wconv_kernel<<<(COUT * CIN * KW + 255) / 256, 256, 0, stream>>>(conv_w, Wt);
    dim3 grid(LEN / (64 * NT), BATCH);
    conv_kernel<<<grid, 256, 0, stream>>>(I, bn_g, bn_b, bn_m, bn_v, Wt, alpha, prelu, out);
}